// Round 7
// baseline (169.735 us; speedup 1.0000x reference)
//
#include <hip/hip_runtime.h>
#include <math.h>

#define TOPK 13
#define PI_F 3.14159265358979323846f
#define K1_WAVES 4

typedef unsigned int u32;
typedef unsigned long long u64;

// monotone float -> uint mapping matching XLA total order
__device__ __forceinline__ u32 ford(float f) {
    u32 u = __float_as_uint(f);
    return (u & 0x80000000u) ? ~u : (u | 0x80000000u);
}
__device__ __forceinline__ float funord(u32 o) {
    u32 u = (o & 0x80000000u) ? (o & 0x7FFFFFFFu) : ~o;
    return __uint_as_float(u);
}

__device__ __forceinline__ float iou_fn(float4 g, float4 p) {
    float ltx = fmaxf(g.x, p.x), lty = fmaxf(g.y, p.y);
    float rbx = fminf(g.z, p.z), rby = fminf(g.w, p.w);
    float inter = fmaxf(rbx - ltx, 0.0f) * fmaxf(rby - lty, 0.0f);
    float a1 = fmaxf(g.z - g.x, 0.0f) * fmaxf(g.w - g.y, 0.0f);
    float a2 = fmaxf(p.z - p.x, 0.0f) * fmaxf(p.w - p.y, 0.0f);
    return inter / (((a1 + a2) - inter) + 1e-9f);
}

struct RowParams { float av, bar, offc, mx, mn; };

__device__ __forceinline__ RowParams row_params(float4 g) {
    float w = g.z - g.x, h = g.w - g.y;
    float ar = w / (h + 1e-5f);
    float ia = 1.0f / ar;
    RowParams rp;
    rp.av = ia / (2.0f - ia);
    rp.bar = 2.0f / ar;
    rp.offc = PI_F * (1.0f - 2.0f / (2.0f * ar));
    rp.mx = 0.5f + 0.5f * cosf(rp.offc);
    rp.mn = 0.5f + 0.5f * cosf(rp.bar * 90.0f / 180.0f * PI_F + rp.offc);
    return rp;
}

__device__ __forceinline__ float ang_measure(const RowParams& rp, float theta) {
    float cfv = 0.5f + 0.5f * cosf(rp.bar * theta / 180.0f * PI_F + rp.offc);
    float r = (cfv - rp.mn) / (rp.mx - rp.mn) * (1.0f - rp.av) + rp.av;
    return isnan(r) ? 0.0f : r;
}

// align in exact reference op order: (s**1 * iou**5) * ang**3, left-assoc
__device__ __forceinline__ float align_fn(float s, float iou, float r) {
    float iou2 = iou * iou;
    float iou5 = (iou2 * iou2) * iou;
    float r3 = (r * r) * r;
    return (s * iou5) * r3;
}

__device__ __forceinline__ void insert13(u64* arr, u64 key) {
    if (key > arr[TOPK - 1]) {
#pragma unroll
        for (int jj = 0; jj < TOPK; jj++) {
            u64 hi = arr[jj] > key ? arr[jj] : key;
            u64 lo = arr[jj] > key ? key : arr[jj];
            arr[jj] = hi;
            key = lo;
        }
    }
}

__global__ void k0_init(int* cnt, int* assign1, u32* pam, u32* pov, int BA, int BN) {
    int t = blockIdx.x * blockDim.x + threadIdx.x;
    if (t < BA) { cnt[t] = 0; assign1[t] = -1; }
    if (t < BN) { pam[t] = 0x80000000u; pov[t] = 0x80000000u; } // ord(+0.0f)
}

// ---------------------------------------------------------------------------
// k1: one block per (batch, gt-row), 4 waves. 1-deep software pipeline on the
// streaming loads (pbox/pang/anc, clamped, unconditional) AND on the
// scattered score load, speculatively issued for inGt lanes one iteration
// ahead (inGt computable from the prefetched anchor point alone — r4 proved
// this lifts VALUBusy 35->60%; r6's stride-256 shape avoids r4's 8x warm-up
// cosf). The prefetched s is the identical address/value the rare path would
// load; extra loads for inGt&&iou==0 lanes have no side effects. Also hides
// the 43 MB ts zero-fill (one fire-and-forget float4 store per iteration),
// so k3 only writes 3.8 MB + one scattered element per fg anchor.
// Classification logic byte-identical to the round-3/6 passing kernels.
// ---------------------------------------------------------------------------
__global__ __launch_bounds__(256)
void k1_topk(const float* __restrict__ scores, const float* __restrict__ pbox,
             const float* __restrict__ pang, const float* __restrict__ anc,
             const int* __restrict__ glab, const float* __restrict__ gbox,
             const float* __restrict__ gang, const float* __restrict__ mgt,
             int* __restrict__ cnt, int* __restrict__ assign1,
             float* __restrict__ out,
             int bs, int A, int n, int C) {
    int j = blockIdx.x;
    // XCD clustering: blocks of the same batch land on the same XCD (j % 8 == b % 8)
    int b = j % bs;
    int i = j / bs;
    int bi = b * n + i;
    int tid = threadIdx.x;
    int BA = bs * A;

    // ts zero-fill chunk for this block (hidden under the anchor scan)
    int nF4 = BA * (C / 4);
    int zCH = (nF4 + gridDim.x - 1) / gridDim.x;
    int zBeg = j * zCH + tid;
    int zEnd = min(j * zCH + zCH, nF4);
    float4* tsf4 = (float4*)(out + (size_t)BA * 6);
    const float4 z4 = make_float4(0.0f, 0.0f, 0.0f, 0.0f);

    float mg = mgt[bi];
    if (!(mg > 0.0f)) {
        // masked row contributes no candidates, but still owns its ts chunk
        for (; zBeg < zEnd; zBeg += 256) tsf4[zBeg] = z4;
        return;
    }

    float4 g = ((const float4*)gbox)[bi];
    int lab = glab[bi];
    float ga = gang[bi];
    RowParams rp = row_params(g);

    const float4* pb = ((const float4*)pbox) + (size_t)b * A;
    const float* pa = pang + (size_t)b * A;
    const float2* ac = (const float2*)anc;
    const float* sc = scores + (size_t)b * A * C + lab;

    u64 arr[TOPK];
#pragma unroll
    for (int jj = 0; jj < TOPK; jj++) arr[jj] = 0ull;
    u64 zkey = 0ull;  // thread's lowest-index exact-+0 candidate

    // prologue: stage iteration 0 (tid < 256 <= A, so a is valid)
    int a = tid;
    float4 p = pb[a];
    float pav = pa[a];
    float2 apt = ac[a];
    float mnv = fminf(fminf(apt.x - g.x, apt.y - g.y), fminf(g.z - apt.x, g.w - apt.y));
    bool inG = (mnv > 1e-9f);           // a < A always true in prologue
    float s = 0.0f;
    if (inG) s = sc[(size_t)a * C];     // speculative scatter prefetch

    // Exactness of the conditional-r path (reference v = align*in_gts,
    // align = (s*iou^5)*r^3, s>=0, iou>=0, r finite after NaN-replace):
    //  - !inGt or iou==0  -> v = +/-0 with sign(r); selectable only if +0.
    //  - inGt && iou>0    -> r>0: v = align (insert if >0, else +0 cand);
    //                       r==0: +0 cand; r<0: v<0 never selectable.
    //  sign(r) only consumed while zkey unset -> cosf skipped afterwards.
    int nit = (A + 255) >> 8;          // uniform trip count; tail guarded by `valid`
    int clampA = A - 1;
    for (int it = 0; it < nit; ++it) {
        // stage iteration it+1 (clamped, unconditional -> pipelineable)
        int an = a + 256;
        int can = min(an, clampA);
        float4 p2 = pb[can];
        float pav2 = pa[can];
        float2 apt2 = ac[can];
        // hidden zero-fill store (independent, fire-and-forget)
        if (zBeg < zEnd) { tsf4[zBeg] = z4; zBeg += 256; }
        float mnv2 = fminf(fminf(apt2.x - g.x, apt2.y - g.y),
                           fminf(g.z - apt2.x, g.w - apt2.y));
        bool inG2 = (mnv2 > 1e-9f) && (an < A);
        float s2 = 0.0f;
        if (inG2) s2 = sc[(size_t)can * C];   // speculative scatter prefetch

        // consume iteration it (all operands already resident)
        bool valid = a < A;
        float iou = iou_fn(g, p);
        bool needAlign = inG && (iou > 0.0f) && valid;
        if (needAlign || (zkey == 0ull && valid)) {
            float th = fabsf(ga - pav);
            float r = ang_measure(rp, th);
            bool zeroCand;
            if (needAlign && r > 0.0f) {
                float v = align_fn(s, iou, r);   // s prefetched (same address/value)
                if (v > 0.0f) {
                    zeroCand = false;
                    insert13(arr, ((u64)ford(v) << 32) | (u64)(0xFFFFFFFFu - (u32)a));
                } else {
                    zeroCand = true;  // s==0 or iou^5 underflow -> v == +0 exactly
                }
            } else {
                zeroCand = (r >= 0.0f);  // v == sign(r)*0; only +0 is selectable
            }
            if (zeroCand && zkey == 0ull) {
                zkey = (0x80000000ull << 32) | (u64)(0xFFFFFFFFu - (u32)a);
            }
        }
        a = an; p = p2; pav = pav2; mnv = mnv2; inG = inG2; s = s2;
    }
    for (; zBeg < zEnd; zBeg += 256) tsf4[zBeg] = z4;  // drain (normally no-op)
    // merge the single zero candidate (sufficient per thread: the 13
    // lowest-index zero candidates land on distinct threads at stride 256)
    insert13(arr, zkey);

    // Phase 1: per-wave top-13 (no barriers; keys unique, 0 = empty).
    __shared__ u64 wtop[K1_WAVES * TOPK];
    int lane = tid & 63, wv = tid >> 6;
    for (int round = 0; round < TOPK; round++) {
        u64 m = arr[0];
#pragma unroll
        for (int st = 32; st > 0; st >>= 1) {
            u64 o = __shfl_xor(m, st, 64);
            if (o > m) m = o;
        }
        if (lane == 0) wtop[wv * TOPK + round] = m;
        if (arr[0] == m && m != 0ull) {  // unique winner pops its head
#pragma unroll
            for (int jj = 0; jj < TOPK - 1; jj++) arr[jj] = arr[jj + 1];
            arr[TOPK - 1] = 0ull;
        }
    }
    __syncthreads();

    // Phase 2: wave 0 merges the 4 sorted 13-lists (52 keys, one per lane)
    // and fires the atomics for the block top-13.
    if (wv == 0) {
        const int NK = K1_WAVES * TOPK;  // 52
        u64 ka = (lane < NK) ? wtop[lane] : 0ull;
        for (int round = 0; round < TOPK; round++) {
            u64 m = ka;
#pragma unroll
            for (int st = 32; st > 0; st >>= 1) {
                u64 o = __shfl_xor(m, st, 64);
                if (o > m) m = o;
            }
            if (m == 0ull) break;        // uniform across wave 0 -> safe
            if (ka == m) {               // unique owner lane processes the winner
                ka = 0ull;
                int aa = (int)(0xFFFFFFFFu - (u32)(m & 0xFFFFFFFFull));
                float2 ap2 = ac[aa];
                float mnw = fminf(fminf(ap2.x - g.x, ap2.y - g.y),
                                  fminf(g.z - ap2.x, g.w - ap2.y));
                if (mnw > 1e-9f) {  // mask_pos = mask_topk * in_gts * mask_gt
                    atomicAdd(&cnt[(size_t)b * A + aa], 1);
                    atomicMax(&assign1[(size_t)b * A + aa], i);
                }
            }
        }
    }
}

__global__ __launch_bounds__(256)
void k2_resolve(const float* __restrict__ scores, const float* __restrict__ pbox,
                const float* __restrict__ pang, const int* __restrict__ glab,
                const float* __restrict__ gbox, const float* __restrict__ gang,
                const int* __restrict__ cnt, const int* __restrict__ assign1,
                int* __restrict__ assign, float* __restrict__ alignv,
                u32* __restrict__ pam, u32* __restrict__ pov,
                int bs, int A, int n, int C) {
    int t = blockIdx.x * blockDim.x + threadIdx.x;
    if (t >= bs * A) return;
    int b = t / A;
    int c = cnt[t];
    int asg = -1;
    float alv = 0.0f;
    if (c > 0) {
        float4 p = ((const float4*)pbox)[t];
        if (c == 1) {
            asg = assign1[t];
        } else {
            // reference: overlaps.argmax(1) over ALL gt rows, first-max tie-break
            float best = -1.0f;
            asg = 0;
            for (int i = 0; i < n; i++) {
                float4 gi = ((const float4*)gbox)[b * n + i];
                float io = iou_fn(gi, p);
                if (io > best) { best = io; asg = i; }
            }
        }
        float4 g = ((const float4*)gbox)[b * n + asg];
        RowParams rp = row_params(g);
        float iou = iou_fn(g, p);
        float th = fabsf(gang[b * n + asg] - pang[t]);
        float r = ang_measure(rp, th);
        float s = scores[(size_t)t * C + glab[b * n + asg]];
        alv = align_fn(s, iou, r);
        atomicMax(&pam[b * n + asg], ford(alv));
        atomicMax(&pov[b * n + asg], ford(iou));
    }
    assign[t] = asg;
    alignv[t] = alv;
}

// ---------------------------------------------------------------------------
// k3: outputs. ts zeros were pre-written by k1; only writes tlab/tbb/tang/fg
// (3.8 MB) plus ONE scattered ts element per fg anchor.
// ---------------------------------------------------------------------------
__global__ __launch_bounds__(256)
void k3_out(const int* __restrict__ glab, const float* __restrict__ gbox,
            const float* __restrict__ gang, const int* __restrict__ assign,
            const float* __restrict__ alignv, const u32* __restrict__ pam,
            const u32* __restrict__ pov, float* __restrict__ out,
            int bs, int A, int n, int C) {
    int t = blockIdx.x * blockDim.x + threadIdx.x;
    int BA = bs * A;
    if (t >= BA) return;
    int b = t / A;
    int asg = assign[t];
    bool fg = asg >= 0;
    int tgt = fg ? asg : 0;  // argmax of all-zero column -> row 0
    int lb = glab[b * n + tgt];
    if (lb < 0) lb = 0;

    out[t] = (float)lb;                                             // tlab
    ((float4*)(out + BA))[t] = ((const float4*)gbox)[b * n + tgt];  // tbb
    out[(size_t)BA * 5 + t] = gang[b * n + tgt];                    // tang
    out[(size_t)BA * 6 + (size_t)BA * C + t] = fg ? 1.0f : 0.0f;    // fg

    if (fg) {
        float pamv = funord(pam[b * n + asg]);
        float povv = funord(pov[b * n + asg]);
        float vv = (alignv[t] * povv) / (pamv + 1e-9f);
        // one_hot row: zeros pre-written by k1; single nonzero element.
        // (59 other gt rows contribute exactly 0 to the reference max.)
        out[(size_t)BA * 6 + (size_t)t * C + lb] = fmaxf(vv, 0.0f);
    }
}

extern "C" void kernel_launch(void* const* d_in, const int* in_sizes, int n_in,
                              void* d_out, int out_size, void* d_ws, size_t ws_size,
                              hipStream_t stream) {
    const float* scores = (const float*)d_in[0];
    const float* pbox = (const float*)d_in[1];
    const float* pang = (const float*)d_in[2];
    const float* anc = (const float*)d_in[3];
    const int* glab = (const int*)d_in[4];
    const float* gbox = (const float*)d_in[5];
    const float* gang = (const float*)d_in[6];
    const float* mgt = (const float*)d_in[7];

    const int C = 80;
    int A = in_sizes[3] / 2;
    int bs = in_sizes[0] / (A * C);
    int n = in_sizes[4] / bs;
    int BA = bs * A;
    int BN = bs * n;

    char* ws = (char*)d_ws;
    int* cnt = (int*)ws;        ws += sizeof(int) * (size_t)BA;
    int* assign1 = (int*)ws;    ws += sizeof(int) * (size_t)BA;
    int* assign = (int*)ws;     ws += sizeof(int) * (size_t)BA;
    float* alignv = (float*)ws; ws += sizeof(float) * (size_t)BA;
    u32* pam = (u32*)ws;        ws += sizeof(u32) * (size_t)BN;
    u32* pov = (u32*)ws;        ws += sizeof(u32) * (size_t)BN;

    k0_init<<<(BA + 255) / 256, 256, 0, stream>>>(cnt, assign1, pam, pov, BA, BN);
    k1_topk<<<BN, 256, 0, stream>>>(scores, pbox, pang, anc, glab, gbox, gang, mgt,
                                    cnt, assign1, (float*)d_out, bs, A, n, C);
    k2_resolve<<<(BA + 255) / 256, 256, 0, stream>>>(scores, pbox, pang, glab, gbox, gang,
                                                     cnt, assign1, assign, alignv, pam, pov,
                                                     bs, A, n, C);
    k3_out<<<(BA + 255) / 256, 256, 0, stream>>>(glab, gbox, gang, assign, alignv, pam, pov,
                                                 (float*)d_out, bs, A, n, C);
}